// Round 8
// baseline (227.974 us; speedup 1.0000x reference)
//
#include <hip/hip_runtime.h>
#include <hip/hip_fp16.h>

// AttentionQV0: LN -> QKV -> QK^T -> dw-convs -> 1x1 conv+BN+SiLU+softmax(fused) -> PV -> out proj
// B=2,P=2,N=1024,DIM=256,HEADS=8,DH=64,HW=32,C=1024. 32 "images" of 1024x1024 scores.
// Workspace: region0 64MB (D -> P), region1 64MB (AC), statics ~21MB.

#define DEV __device__ __forceinline__

typedef __attribute__((ext_vector_type(8))) _Float16 f16x8;
typedef __attribute__((ext_vector_type(4))) float f32x4;

DEV float h2f_bits(unsigned short u) { __half h; *reinterpret_cast<unsigned short*>(&h) = u; return __half2float(h); }
DEV unsigned short f2h_bits(float f) { __half h = __float2half(f); return *reinterpret_cast<unsigned short*>(&h); }

// ---------------- prep: cast/transpose weights to f16 ----------------
__global__ __launch_bounds__(256) void prep_kernel(
    const float* __restrict__ wqkv, const float* __restrict__ w1x1,
    const float* __restrict__ wout,
    __half* __restrict__ WQKVT, __half* __restrict__ W1X1H, __half* __restrict__ WOTT) {
  int i0 = blockIdx.x * 256 + threadIdx.x;
  int stride = gridDim.x * 256;
  for (int i = i0; i < 1536 * 256; i += stride) {          // WQKVT[j][k] = wqkv[k][j]
    int j = i >> 8, k = i & 255;
    WQKVT[i] = __float2half(wqkv[k * 1536 + j]);
  }
  for (int i = i0; i < 1024 * 1024; i += stride)           // straight cast (row o, col c)
    W1X1H[i] = __float2half(w1x1[i]);
  for (int i = i0; i < 256 * 512; i += stride) {           // WOTT[j][k] = wout[k][j]
    int j = i >> 9, k = i & 511;
    WOTT[i] = __float2half(wout[k * 256 + j]);
  }
}

// ---------------- LayerNorm (row = token, 256 threads) ----------------
__global__ __launch_bounds__(256) void ln_kernel(const float* __restrict__ x,
    const float* __restrict__ g, const float* __restrict__ b, __half* __restrict__ XN) {
  int row = blockIdx.x;
  int tid = threadIdx.x, lane = tid & 63, wid = tid >> 6;
  float xv = x[(size_t)row * 256 + tid];
  float s = xv, q = xv * xv;
#pragma unroll
  for (int off = 32; off; off >>= 1) { s += __shfl_xor(s, off); q += __shfl_xor(q, off); }
  __shared__ float rs[4], rq[4];
  if (lane == 0) { rs[wid] = s; rq[wid] = q; }
  __syncthreads();
  s = rs[0] + rs[1] + rs[2] + rs[3];
  q = rq[0] + rq[1] + rq[2] + rq[3];
  float mu = s * (1.f / 256.f);
  float var = q * (1.f / 256.f) - mu * mu;
  float r = rsqrtf(var + 1e-5f);
  XN[(size_t)row * 256 + tid] = __float2half((xv - mu) * r * g[tid] + b[tid]);
}

// ---------------- generic BT GEMM (128-wide tiles, 4 waves): small GEMMs ----------------
template <int BM, int BN, int BK, int WGN, int FM, int FN, class Epi>
__global__ __launch_bounds__(256) void gemm_bt(
    const __half* __restrict__ A, long long aStride,
    const __half* __restrict__ B, long long bStride,
    int K, Epi epi) {
  constexpr int CPR = BK / 8;                 // 16B chunks per row
  constexpr int NCA = (BM * BK) / (8 * 256);
  constexpr int NCB = (BN * BK) / (8 * 256);
  constexpr int KSUB = BK / 32;               // mfma k-steps per tile
  __shared__ __align__(16) __half smA[2][BM * BK];
  __shared__ __align__(16) __half smB[2][BN * BK];
  const int tid = threadIdx.x;
  const int lane = tid & 63, wid = tid >> 6;
  const int wr = wid / WGN, wc = wid % WGN;
  const int gx = gridDim.x, gxy = gridDim.x * gridDim.y;
  const int nwg = gxy * gridDim.z;
  const int b_lin = blockIdx.x + blockIdx.y * gx + blockIdx.z * gxy;
  const int logical = (b_lin & 7) * (nwg >> 3) + (b_lin >> 3);
  const int bx = logical % gx, by = (logical / gx) % gridDim.y, bz = logical / gxy;
  const int img = bz;
  const int row0 = bx * BM;
  const int col0 = by * BN;
  const __half* Ab = A + (size_t)((long long)img * aStride);
  const __half* Bb = B + (size_t)((long long)img * bStride);
  f32x4 acc[FM][FN] = {};
  const int lr = lane & 15;
  const int kq = lane >> 4;                   // 0..3 (16B chunk within k-sub)

  auto swz = [](int c, int r) -> int {
    return (CPR == 8) ? (c ^ (r & 7)) : (c ^ ((r >> 1) & 3));
  };

  const __half* pA[NCA]; int dA[NCA];
  const __half* pB[NCB]; int dB[NCB];
#pragma unroll
  for (int it = 0; it < NCA; ++it) {
    int e = it * 256 + tid, r = e / CPR, c = e % CPR;
    pA[it] = Ab + (size_t)(row0 + r) * K + swz(c, r) * 8;
    dA[it] = r * BK + c * 8;
  }
#pragma unroll
  for (int it = 0; it < NCB; ++it) {
    int e = it * 256 + tid, r = e / CPR, c = e % CPR;
    pB[it] = Bb + (size_t)(col0 + r) * K + swz(c, r) * 8;
    dB[it] = r * BK + c * 8;
  }

  auto stage = [&](int buf, int kt) {
#pragma unroll
    for (int it = 0; it < NCA; ++it)
      __builtin_amdgcn_global_load_lds(
          (const __attribute__((address_space(1))) unsigned int*)(pA[it] + kt),
          (__attribute__((address_space(3))) unsigned int*)(&smA[buf][dA[it]]),
          16, 0, 0);
#pragma unroll
    for (int it = 0; it < NCB; ++it)
      __builtin_amdgcn_global_load_lds(
          (const __attribute__((address_space(1))) unsigned int*)(pB[it] + kt),
          (__attribute__((address_space(3))) unsigned int*)(&smB[buf][dB[it]]),
          16, 0, 0);
  };

  const int NT = K / BK;
  stage(0, 0);
  __syncthreads();
  int cur = 0;
  for (int t = 0; t < NT; ++t) {
    if (t + 1 < NT) stage(cur ^ 1, (t + 1) * BK);   // prefetch next tile first
#pragma unroll
    for (int kk = 0; kk < KSUB; ++kk) {
      f16x8 av[FM], bv[FN];
#pragma unroll
      for (int i = 0; i < FM; ++i) {
        int row = wr * FM * 16 + i * 16 + lr;
        int ch = swz(kk * 4 + kq, lr);
        av[i] = *reinterpret_cast<const f16x8*>(&smA[cur][row * BK + ch * 8]);
      }
#pragma unroll
      for (int j = 0; j < FN; ++j) {
        int row = wc * FN * 16 + j * 16 + lr;
        int ch = swz(kk * 4 + kq, lr);
        bv[j] = *reinterpret_cast<const f16x8*>(&smB[cur][row * BK + ch * 8]);
      }
#pragma unroll
      for (int i = 0; i < FM; ++i)
#pragma unroll
        for (int j = 0; j < FN; ++j)
          acc[i][j] = __builtin_amdgcn_mfma_f32_16x16x32_f16(av[i], bv[j], acc[i][j], 0, 0, 0);
    }
    __syncthreads();
    cur ^= 1;
  }

  const int orow = row0 + wr * FM * 16 + (lane >> 4) * 4;
  const int ocol = col0 + wc * FN * 16 + lr;
#pragma unroll
  for (int i = 0; i < FM; ++i)
#pragma unroll
    for (int j = 0; j < FN; ++j)
#pragma unroll
      for (int q = 0; q < 4; ++q)
        epi.store(img, orow + i * 16 + q, ocol + j * 16, acc[i][j][q]);
}

// ---------------- epilogues (simple store-based) ----------------
struct EpiQKV {  // rows t in [0,4096), cols j in [0,1536)
  __half *Q, *K, *V;
  DEV void store(int, int t, int j, float v) const {
    int part = j >> 9, inner = j & 511;
    int h = inner >> 6, d = inner & 63;
    int bp = t >> 10, n = t & 1023;
    size_t img = (size_t)(bp * 8 + h);
    if (part == 0)       Q[(img * 1024 + n) * 64 + d] = __float2half(v * 0.125f); // fold DH^-0.5
    else if (part == 1)  K[(img * 1024 + n) * 64 + d] = __float2half(v);
    else                 V[(img * 64 + d) * 1024 + n] = __float2half(v);          // V transposed
  }
};
struct EpiQK {   // D[img][n][m], natural layout
  __half* D;
  DEV void store(int img, int n, int m, float v) const {
    D[((size_t)img << 20) + n * 1024 + m] = __float2half(v);
  }
};
struct EpiPV {   // rows n, cols d -> O[(bp*1024+n)][h*64+d]
  __half* O;
  DEV void store(int img, int n, int d, float v) const {
    int bp = img >> 3, h = img & 7;
    O[((size_t)(bp * 1024 + n)) * 512 + h * 64 + d] = __float2half(v);
  }
};
struct EpiOut {  // rows t, cols j -> out f32 + bias
  float* out; const float* bias;
  DEV void store(int, int t, int j, float v) const {
    out[(size_t)t * 256 + j] = v + bias[j];
  }
};

// ---------------- 256x256-tile 8-wave GEMM for the 1x1 conv (+BN+SiLU+softmax) ----------------
// m201-style phased schedule: per K-tile (BK=32), 4 phases, each
// {2 A ds_reads (+4 B reads in ph0), stage ONE quarter of tile t+3, s_barrier,
//  lgkmcnt(0)+sched_barrier, setprio(1), 8 MFMA, setprio(0), s_barrier}.
// 4 LDS slots (128KB), 3 tiles in flight; counted vmcnt(8) once per iteration
// (never 0 in steady state) + barrier makes per-wave vmcnt globally sufficient.
struct Epi1x1F8 {
  __half* P;
  const float *g, *b, *m, *vv;
  DEV void finalize(int img, int ob, int cb, int lane, f32x4 (&acc)[8][4]) const {
    const int lr = lane & 15, kq = lane >> 4;
    __half* Pi = P + ((size_t)img << 20);
#pragma unroll
    for (int ih = 0; ih < 4; ++ih) {           // 32-row o-block within wave
#pragma unroll
      for (int sh = 0; sh < 2; ++sh) {         // 32-col s-block within wave
        float v[2][2][4];
        float mx = -1e30f;
#pragma unroll
        for (int di = 0; di < 2; ++di) {
          int i = ih * 2 + di;
#pragma unroll
          for (int q = 0; q < 4; ++q) {
            int o = ob + i * 16 + kq * 4 + q;
            float sc = rsqrtf(vv[o] + 1e-5f) * g[o];
            float mo = m[o], bo = b[o];
#pragma unroll
            for (int dj = 0; dj < 2; ++dj) {
              float t = (acc[i][sh * 2 + dj][q] - mo) * sc + bo;
              t = t / (1.f + __expf(-t));       // SiLU
              v[di][dj][q] = t;
              mx = fmaxf(mx, t);
            }
          }
        }
#pragma unroll
        for (int off = 32; off; off >>= 1) mx = fmaxf(mx, __shfl_xor(mx, off));
        float sm = 0.f;
#pragma unroll
        for (int di = 0; di < 2; ++di)
#pragma unroll
          for (int dj = 0; dj < 2; ++dj)
#pragma unroll
            for (int q = 0; q < 4; ++q) {
              float e = __expf(v[di][dj][q] - mx);
              v[di][dj][q] = e; sm += e;
            }
#pragma unroll
        for (int off = 32; off; off >>= 1) sm += __shfl_xor(sm, off);
        float inv = 1.f / sm;
#pragma unroll
        for (int di = 0; di < 2; ++di) {
          int i = ih * 2 + di;
#pragma unroll
          for (int q = 0; q < 4; ++q) {
            int o = ob + i * 16 + kq * 4 + q;
            size_t nhi = (size_t)(o >> 5) * 32;
            int mlo = (o & 31) * 32;
#pragma unroll
            for (int dj = 0; dj < 2; ++dj) {
              int s = cb + (sh * 2 + dj) * 16 + lr;
              Pi[(nhi + (s >> 5)) * 1024 + mlo + (s & 31)] = __float2half(v[di][dj][q] * inv);
            }
          }
        }
      }
    }
  }
};

template <class Epi>
__global__ __launch_bounds__(512, 1) void gemm8(
    const __half* __restrict__ A, long long aStride,
    const __half* __restrict__ B, long long bStride,
    int K, Epi epi) {
  __shared__ __align__(16) __half smA[4][256 * 32];
  __shared__ __align__(16) __half smB[4][256 * 32];
  const int tid = threadIdx.x;
  const int lane = tid & 63, wid = tid >> 6;
  const int wr = wid >> 2, wc = wid & 3;
  // XCD swizzle (nwg = 512, %8==0)
  const int gx = gridDim.x, gxy = gx * gridDim.y;
  const int nwg = gxy * gridDim.z;
  const int b_lin = blockIdx.x + blockIdx.y * gx + blockIdx.z * gxy;
  const int logical = (b_lin & 7) * (nwg >> 3) + (b_lin >> 3);
  const int bx = logical % gx, by = (logical / gx) % gridDim.y, bz = logical / gxy;
  const int img = bz, row0 = bx * 256, col0 = by * 256;
  const __half* Ab = A + (size_t)((long long)img * aStride);
  const __half* Bb = B + (size_t)((long long)img * bStride);

  // staging: waves 0-3 own A, waves 4-7 own B; each thread covers 4 row-quarters.
  const int tau = tid & 255;
  const bool grpB = (tid >= 256);
  const __half* Mb = grpB ? Bb : Ab;
  const int rc0 = grpB ? col0 : row0;
  const int cch = tau & 3;
  const int swc = cch ^ ((tau >> 3) & 3);     // (r>>1)&3 with r=(tau>>2)+64s
  const __half* pg[4]; int dstoff[4];
#pragma unroll
  for (int s = 0; s < 4; ++s) {
    int r = (tau >> 2) + 64 * s;
    pg[s] = Mb + (size_t)(rc0 + r) * K + swc * 8;
    dstoff[s] = r * 32 + cch * 8;
  }
  __half* smDst = grpB ? &smB[0][0] : &smA[0][0];
  auto stage1 = [&](int buf, int kt, int s) {
    __builtin_amdgcn_global_load_lds(
        (const __attribute__((address_space(1))) unsigned int*)(pg[s] + kt),
        (__attribute__((address_space(3))) unsigned int*)(smDst + buf * 8192 + dstoff[s]),
        16, 0, 0);
  };
  auto stageTile = [&](int buf, int kt) {
#pragma unroll
    for (int s = 0; s < 4; ++s) stage1(buf, kt, s);
  };

  const int lr = lane & 15, kq = lane >> 4;
  const int ch = kq ^ ((lr >> 1) & 3);        // read-side swizzle
  const int aOff = (wr * 128 + lr) * 32 + ch * 8;   // + i*512
  const int bOff = (wc * 64 + lr) * 32 + ch * 8;    // + j*512
  f32x4 acc[8][4] = {};

  const int NT = K / 32;                      // 32 tiles
  // prologue: stage tiles 0..2 (12 loads/thread in flight), wait tile 0 home
  stageTile(0, 0); stageTile(1, 32); stageTile(2, 64);
  asm volatile("s_waitcnt vmcnt(8)" ::: "memory");
  __builtin_amdgcn_sched_barrier(0);
  __builtin_amdgcn_s_barrier();
  __builtin_amdgcn_sched_barrier(0);

  for (int t = 0; t < NT; ++t) {
    const int b = t & 3;
    const __half* sA = &smA[b][0];
    const __half* sB = &smB[b][0];
    const bool pf = (t + 3 < NT);
    const int pfb = (t + 3) & 3;
    const int pfk = (t + 3) * 32;
    f16x8 bv[4];
#pragma unroll
    for (int ph = 0; ph < 4; ++ph) {
      // ---- phase ph: ds-reads + 1 stage quarter, then barrier/wait/MFMA/barrier
      f16x8 a0 = *reinterpret_cast<const f16x8*>(&sA[aOff + (2 * ph + 0) * 512]);
      f16x8 a1 = *reinterpret_cast<const f16x8*>(&sA[aOff + (2 * ph + 1) * 512]);
      if (ph == 0) {
#pragma unroll
        for (int j = 0; j < 4; ++j)
          bv[j] = *reinterpret_cast<const f16x8*>(&sB[bOff + j * 512]);
      }
      if (pf) stage1(pfb, pfk, ph);
      __builtin_amdgcn_sched_barrier(0);
      __builtin_amdgcn_s_barrier();
      asm volatile("s_waitcnt lgkmcnt(0)" ::: "memory");
      __builtin_amdgcn_sched_barrier(0);
      __builtin_amdgcn_s_setprio(1);
#pragma unroll
      for (int j = 0; j < 4; ++j)
        acc[2 * ph + 0][j] = __builtin_amdgcn_mfma_f32_16x16x32_f16(a0, bv[j], acc[2 * ph + 0][j], 0, 0, 0);
#pragma unroll
      for (int j = 0; j < 4; ++j)
        acc[2 * ph + 1][j] = __builtin_amdgcn_mfma_f32_16x16x32_f16(a1, bv[j], acc[2 * ph + 1][j], 0, 0, 0);
      __builtin_amdgcn_s_setprio(0);
      __builtin_amdgcn_sched_barrier(0);
      __builtin_amdgcn_s_barrier();
      __builtin_amdgcn_sched_barrier(0);
    }
    // iteration end: counted wait (tile t+1 home; t+2,t+3 stay in flight), then
    // barrier -> per-wave vmcnt becomes a global guarantee for next iter's reads.
    if (t + 1 < NT) {
      __builtin_amdgcn_sched_barrier(0);
      if (t + 3 < NT)      asm volatile("s_waitcnt vmcnt(8)" ::: "memory");
      else if (t + 2 < NT) asm volatile("s_waitcnt vmcnt(4)" ::: "memory");
      else                 asm volatile("s_waitcnt vmcnt(0)" ::: "memory");
      __builtin_amdgcn_sched_barrier(0);
      __builtin_amdgcn_s_barrier();
      __builtin_amdgcn_sched_barrier(0);
    }
  }
  epi.finalize(img, row0 + wr * 128, col0 + wc * 64, lane, acc);
}

// ---------------- fused depthwise convs as LDS-tiled transpose ----------------
__global__ __launch_bounds__(256) void conv_t_kernel(const __half* __restrict__ D,
    const float* __restrict__ wc1, const float* __restrict__ wc2,
    __half* __restrict__ AC) {
  const int img = blockIdx.x >> 5, h1 = blockIdx.x & 31;
  const __half* Di = D + ((size_t)img << 20) + (size_t)h1 * 32768;  // rows n = h1*32 + w1
  __half* ACi = AC + ((size_t)img << 20) + h1 * 32;
  const int tid = threadIdx.x;
  const int h2 = tid >> 3;          // channel-in-block (fixed per thread)
  const int w2 = (tid & 7) * 4;     // first w2 of this thread's 4 elems
  const int m = tid * 4;            // = h2*32 + w2
  const int c = h1 * 32 + h2;
  const float u0 = wc1[2 * c], u1 = wc1[2 * c + 1];   // conv along w2
  const float v0 = wc2[2 * c], v1 = wc2[2 * c + 1];   // conv along w1
  const int w2o = tid >> 3, h2o = (tid & 7) * 4;      // write-phase mapping
  __shared__ __half T[32][36];                        // [w2][h2], padded
  for (int w1 = 0; w1 < 32; ++w1) {
    const int w1n = (w1 < 31) ? w1 + 1 : 30;          // reflect bottom
    const __half* r0 = Di + w1 * 1024;
    const __half* r1 = Di + w1n * 1024;
    float a0[5], a1[5];
    ushort4 x0 = *reinterpret_cast<const ushort4*>(r0 + m);
    ushort4 x1 = *reinterpret_cast<const ushort4*>(r1 + m);
    a0[0] = h2f_bits(x0.x); a0[1] = h2f_bits(x0.y); a0[2] = h2f_bits(x0.z); a0[3] = h2f_bits(x0.w);
    a1[0] = h2f_bits(x1.x); a1[1] = h2f_bits(x1.y); a1[2] = h2f_bits(x1.z); a1[3] = h2f_bits(x1.w);
    if (w2 != 28) { a0[4] = __half2float(r0[m + 4]); a1[4] = __half2float(r1[m + 4]); }
    else          { a0[4] = 0.f;                      a1[4] = 0.f; }
#pragma unroll
    for (int j = 0; j < 4; ++j) {
      int jn = (w2 + j < 31) ? j + 1 : j - 1;         // reflect right (w2=31 -> 30)
      float val = v0 * (u0 * a0[j] + u1 * a0[jn]) + v1 * (u0 * a1[j] + u1 * a1[jn]);
      T[w2 + j][h2] = __float2half(val);
    }
    __syncthreads();
    ushort4 o = *reinterpret_cast<const ushort4*>(&T[w2o][h2o]);
    *reinterpret_cast<ushort4*>(ACi + (size_t)(w1 * 32 + w2o) * 1024 + h2o) = o;
    __syncthreads();
  }
}

extern "C" void kernel_launch(void* const* d_in, const int* in_sizes, int n_in,
                              void* d_out, int out_size, void* d_ws, size_t ws_size,
                              hipStream_t stream) {
  const float* x     = (const float*)d_in[0];
  const float* ln_g  = (const float*)d_in[1];
  const float* ln_b  = (const float*)d_in[2];
  const float* w_qkv = (const float*)d_in[3];
  const float* wc1   = (const float*)d_in[4];
  const float* wc2   = (const float*)d_in[5];
  const float* w1x1  = (const float*)d_in[6];
  const float* bn_g  = (const float*)d_in[7];
  const float* bn_b  = (const float*)d_in[8];
  const float* bn_m  = (const float*)d_in[9];
  const float* bn_v  = (const float*)d_in[10];
  const float* w_out = (const float*)d_in[11];
  const float* b_out = (const float*)d_in[12];
  float* out = (float*)d_out;

  const size_t MB = 1024 * 1024;
  char* ws = (char*)d_ws;
  // region0 (64MB): D (QK output), later overwritten by P (fused 1x1 output)
  __half* Db = (__half*)ws;
  __half* Pb = (__half*)ws;
  // region1 (64MB): Aconv^T
  __half* ACb = (__half*)(ws + 64 * MB);
  // statics
  char* p = ws + 128 * MB;
  __half* XN    = (__half*)p; p += 2 * MB;            // 4096x256
  __half* WQKVT = (__half*)p; p += 1536 * 256 * 2;    // 1536x256
  __half* W1X1H = (__half*)p; p += 2 * MB;            // 1024x1024
  __half* WOTT  = (__half*)p; p += 256 * 512 * 2;     // 256x512
  __half* Qb    = (__half*)p; p += 4 * MB;            // 32x1024x64 (scaled)
  __half* Kb    = (__half*)p; p += 4 * MB;            // 32x1024x64
  __half* Vtb   = (__half*)p; p += 4 * MB;            // 32x64x1024
  __half* Ob    = (__half*)p; p += 4 * MB;            // 4096x512

  prep_kernel<<<2048, 256, 0, stream>>>(w_qkv, w1x1, w_out, WQKVT, W1X1H, WOTT);
  ln_kernel<<<4096, 256, 0, stream>>>(x, ln_g, ln_b, XN);

  { EpiQKV e{Qb, Kb, Vtb};
    gemm_bt<128, 128, 64, 2, 4, 4, EpiQKV><<<dim3(32, 12, 1), 256, 0, stream>>>(
        XN, 0, WQKVT, 0, 256, e); }

  { EpiQK e{Db};
    gemm_bt<128, 128, 64, 2, 4, 4, EpiQK><<<dim3(8, 8, 32), 256, 0, stream>>>(
        Qb, 65536, Kb, 65536, 64, e); }

  conv_t_kernel<<<1024, 256, 0, stream>>>(Db, wc1, wc2, ACb);

  { Epi1x1F8 e{Pb, bn_g, bn_b, bn_m, bn_v};
    gemm8<Epi1x1F8><<<dim3(4, 4, 32), 512, 0, stream>>>(
        W1X1H, 0, ACb, 1 << 20, 1024, e); }

  { EpiPV e{Ob};
    gemm_bt<128, 64, 64, 2, 4, 2, EpiPV><<<dim3(8, 1, 32), 256, 0, stream>>>(
        Pb, 1 << 20, Vtb, 65536, 1024, e); }

  { EpiOut e{out, b_out};
    gemm_bt<128, 128, 64, 2, 4, 4, EpiOut><<<dim3(32, 2, 1), 256, 0, stream>>>(
        Ob, 0, WOTT, 0, 512, e); }
}

// Round 9
// 196.596 us; speedup vs baseline: 1.1596x; 1.1596x over previous
//
#include <hip/hip_runtime.h>
#include <hip/hip_fp16.h>

// AttentionQV0: LN -> QKV -> [QK^T + dw-convs fused] -> 1x1 conv+BN+SiLU+softmax(fused) -> PV -> out proj
// B=2,P=2,N=1024,DIM=256,HEADS=8,DH=64,HW=32,C=1024. 32 "images" of 1024x1024 scores.
// D (QK scores) never hits HBM: conv runs in the QK epilogue from LDS.
// AC uses a permuted channel axis c' = (bx*4+by)*32 + a*8 + b (a=h1&3 within 4-block,
// b=h2&7 within 8-block); W1X1H's K axis is permuted identically in prep -> GEMM invariant.

#define DEV __device__ __forceinline__

typedef __attribute__((ext_vector_type(8))) _Float16 f16x8;
typedef __attribute__((ext_vector_type(4))) float f32x4;
typedef __attribute__((ext_vector_type(8))) unsigned short u16x8;

DEV float h2f_bits(unsigned short u) { __half h; *reinterpret_cast<unsigned short*>(&h) = u; return __half2float(h); }
DEV unsigned short f2h_bits(float f) { __half h = __float2half(f); return *reinterpret_cast<unsigned short*>(&h); }

// ---------------- prep: cast/transpose weights to f16 ----------------
__global__ __launch_bounds__(256) void prep_kernel(
    const float* __restrict__ wqkv, const float* __restrict__ w1x1,
    const float* __restrict__ wout,
    __half* __restrict__ WQKVT, __half* __restrict__ W1X1H, __half* __restrict__ WOTT) {
  int i0 = blockIdx.x * 256 + threadIdx.x;
  int stride = gridDim.x * 256;
  for (int i = i0; i < 1536 * 256; i += stride) {          // WQKVT[j][k] = wqkv[k][j]
    int j = i >> 8, k = i & 255;
    WQKVT[i] = __float2half(wqkv[k * 1536 + j]);
  }
  for (int i = i0; i < 1024 * 1024; i += stride) {         // permuted K axis: col p -> c(p)
    int o = i >> 10, p = i & 1023;
    int blk = p >> 5, r = p & 31, a = r >> 3, bb = r & 7;
    int h1 = (blk >> 2) * 4 + a, h2 = (blk & 3) * 8 + bb;
    W1X1H[i] = __float2half(w1x1[o * 1024 + h1 * 32 + h2]);
  }
  for (int i = i0; i < 256 * 512; i += stride) {           // WOTT[j][k] = wout[k][j]
    int j = i >> 9, k = i & 511;
    WOTT[i] = __float2half(wout[k * 256 + j]);
  }
}

// ---------------- LayerNorm (row = token, 256 threads) ----------------
__global__ __launch_bounds__(256) void ln_kernel(const float* __restrict__ x,
    const float* __restrict__ g, const float* __restrict__ b, __half* __restrict__ XN) {
  int row = blockIdx.x;
  int tid = threadIdx.x, lane = tid & 63, wid = tid >> 6;
  float xv = x[(size_t)row * 256 + tid];
  float s = xv, q = xv * xv;
#pragma unroll
  for (int off = 32; off; off >>= 1) { s += __shfl_xor(s, off); q += __shfl_xor(q, off); }
  __shared__ float rs[4], rq[4];
  if (lane == 0) { rs[wid] = s; rq[wid] = q; }
  __syncthreads();
  s = rs[0] + rs[1] + rs[2] + rs[3];
  q = rq[0] + rq[1] + rq[2] + rq[3];
  float mu = s * (1.f / 256.f);
  float var = q * (1.f / 256.f) - mu * mu;
  float r = rsqrtf(var + 1e-5f);
  XN[(size_t)row * 256 + tid] = __float2half((xv - mu) * r * g[tid] + b[tid]);
}

// ---------------- generic BT GEMM (4 waves): QKV / PV / out ----------------
template <int BM, int BN, int BK, int WGN, int FM, int FN, class Epi>
__global__ __launch_bounds__(256) void gemm_bt(
    const __half* __restrict__ A, long long aStride,
    const __half* __restrict__ B, long long bStride,
    int K, Epi epi) {
  constexpr int CPR = BK / 8;                 // 16B chunks per row
  constexpr int NCA = (BM * BK) / (8 * 256);
  constexpr int NCB = (BN * BK) / (8 * 256);
  constexpr int KSUB = BK / 32;               // mfma k-steps per tile
  __shared__ __align__(16) __half smA[2][BM * BK];
  __shared__ __align__(16) __half smB[2][BN * BK];
  const int tid = threadIdx.x;
  const int lane = tid & 63, wid = tid >> 6;
  const int wr = wid / WGN, wc = wid % WGN;
  const int gx = gridDim.x, gxy = gridDim.x * gridDim.y;
  const int nwg = gxy * gridDim.z;
  const int b_lin = blockIdx.x + blockIdx.y * gx + blockIdx.z * gxy;
  const int logical = (b_lin & 7) * (nwg >> 3) + (b_lin >> 3);
  const int bx = logical % gx, by = (logical / gx) % gridDim.y, bz = logical / gxy;
  const int img = bz;
  const int row0 = bx * BM;
  const int col0 = by * BN;
  const __half* Ab = A + (size_t)((long long)img * aStride);
  const __half* Bb = B + (size_t)((long long)img * bStride);
  f32x4 acc[FM][FN] = {};
  const int lr = lane & 15;
  const int kq = lane >> 4;                   // 0..3 (16B chunk within k-sub)

  auto swz = [](int c, int r) -> int {
    return (CPR == 8) ? (c ^ (r & 7)) : (c ^ ((r >> 1) & 3));
  };

  const __half* pA[NCA]; int dA[NCA];
  const __half* pB[NCB]; int dB[NCB];
#pragma unroll
  for (int it = 0; it < NCA; ++it) {
    int e = it * 256 + tid, r = e / CPR, c = e % CPR;
    pA[it] = Ab + (size_t)(row0 + r) * K + swz(c, r) * 8;
    dA[it] = r * BK + c * 8;
  }
#pragma unroll
  for (int it = 0; it < NCB; ++it) {
    int e = it * 256 + tid, r = e / CPR, c = e % CPR;
    pB[it] = Bb + (size_t)(col0 + r) * K + swz(c, r) * 8;
    dB[it] = r * BK + c * 8;
  }

  auto stage = [&](int buf, int kt) {
#pragma unroll
    for (int it = 0; it < NCA; ++it)
      __builtin_amdgcn_global_load_lds(
          (const __attribute__((address_space(1))) unsigned int*)(pA[it] + kt),
          (__attribute__((address_space(3))) unsigned int*)(&smA[buf][dA[it]]),
          16, 0, 0);
#pragma unroll
    for (int it = 0; it < NCB; ++it)
      __builtin_amdgcn_global_load_lds(
          (const __attribute__((address_space(1))) unsigned int*)(pB[it] + kt),
          (__attribute__((address_space(3))) unsigned int*)(&smB[buf][dB[it]]),
          16, 0, 0);
  };

  const int NT = K / BK;
  stage(0, 0);
  __syncthreads();
  int cur = 0;
  for (int t = 0; t < NT; ++t) {
    if (t + 1 < NT) stage(cur ^ 1, (t + 1) * BK);   // prefetch next tile first
#pragma unroll
    for (int kk = 0; kk < KSUB; ++kk) {
      f16x8 av[FM], bv[FN];
#pragma unroll
      for (int i = 0; i < FM; ++i) {
        int row = wr * FM * 16 + i * 16 + lr;
        int ch = swz(kk * 4 + kq, lr);
        av[i] = *reinterpret_cast<const f16x8*>(&smA[cur][row * BK + ch * 8]);
      }
#pragma unroll
      for (int j = 0; j < FN; ++j) {
        int row = wc * FN * 16 + j * 16 + lr;
        int ch = swz(kk * 4 + kq, lr);
        bv[j] = *reinterpret_cast<const f16x8*>(&smB[cur][row * BK + ch * 8]);
      }
#pragma unroll
      for (int i = 0; i < FM; ++i)
#pragma unroll
        for (int j = 0; j < FN; ++j)
          acc[i][j] = __builtin_amdgcn_mfma_f32_16x16x32_f16(av[i], bv[j], acc[i][j], 0, 0, 0);
    }
    __syncthreads();
    cur ^= 1;
  }

  const int orow = row0 + wr * FM * 16 + (lane >> 4) * 4;
  const int ocol = col0 + wc * FN * 16 + lr;
#pragma unroll
  for (int i = 0; i < FM; ++i)
#pragma unroll
    for (int j = 0; j < FN; ++j)
#pragma unroll
      for (int q = 0; q < 4; ++q)
        epi.store(img, orow + i * 16 + q, ocol + j * 16, acc[i][j][q]);
}

// ---------------- epilogues ----------------
struct EpiQKV {  // rows t in [0,4096), cols j in [0,1536)
  __half *Q, *K, *V;
  DEV void store(int, int t, int j, float v) const {
    int part = j >> 9, inner = j & 511;
    int h = inner >> 6, d = inner & 63;
    int bp = t >> 10, n = t & 1023;
    size_t img = (size_t)(bp * 8 + h);
    if (part == 0)       Q[(img * 1024 + n) * 64 + d] = __float2half(v * 0.125f); // fold DH^-0.5
    else if (part == 1)  K[(img * 1024 + n) * 64 + d] = __float2half(v);
    else                 V[(img * 64 + d) * 1024 + n] = __float2half(v);          // V transposed
  }
};
struct EpiPV {   // rows n, cols d -> O[(bp*1024+n)][h*64+d]
  __half* O;
  DEV void store(int img, int n, int d, float v) const {
    int bp = img >> 3, h = img & 7;
    O[((size_t)(bp * 1024 + n)) * 512 + h * 64 + d] = __float2half(v);
  }
};
struct EpiOut {  // rows t, cols j -> out f32 + bias
  float* out; const float* bias;
  DEV void store(int, int t, int j, float v) const {
    out[(size_t)t * 256 + j] = v + bias[j];
  }
};

// ---------------- fused QK^T + depthwise convs ----------------
// Tile 128 n x 256 m per block, K=64 (single stage). 512 threads = 8 waves (2x4).
// Epilogue: acc -> Dt (transposed [m][n] in LDS, f16) -> 4-tap conv (all neighbors
// tile-local; reflect 31->30 internal) -> transpose buffer T -> coalesced
// AC[s][c'] writes (c' = (bx*4+by)*32 + a*8 + b; 32 consecutive c' = 64B granule).
__global__ __launch_bounds__(512) void qkconv_kernel(
    const __half* __restrict__ Q, const __half* __restrict__ Km,
    const float* __restrict__ wc1, const float* __restrict__ wc2,
    __half* __restrict__ AC) {
  constexpr int NP = 132;                       // Dt inner pad (halfs)
  __shared__ __align__(16) char LDS[77824];     // max(stage 48K, Dt 66K) + T 10K
  __half* smA = (__half*)LDS;                   // [128][64]  16384 B
  __half* smB = (__half*)(LDS + 16384);         // [256][64]  32768 B
  __half* Dt  = (__half*)LDS;                   // [256][132] 67584 B (aliases stage)
  __half* T   = (__half*)(LDS + 67584);         // [4][32][40] 10240 B
  const int tid = threadIdx.x;
  const int lane = tid & 63, wid = tid >> 6;
  const int wr = wid >> 2, wc = wid & 3;
  // XCD swizzle, grid 8 x 4 x 32 = 1024 (%8==0)
  const int gx = gridDim.x, gxy = gx * gridDim.y;
  const int nwg = gxy * gridDim.z;
  const int b_lin = blockIdx.x + blockIdx.y * gx + blockIdx.z * gxy;
  const int logical = (b_lin & 7) * (nwg >> 3) + (b_lin >> 3);
  const int bx = logical % gx, by = (logical / gx) % gridDim.y, bz = logical / gxy;
  const int img = bz, row0 = bx * 128, col0 = by * 256;
  const __half* Qi = Q + ((size_t)img << 16);
  const __half* Ki = Km + ((size_t)img << 16);

  // ---- stage A (128x64) and B (256x64), swizzle c^(r&7) on source ----
#pragma unroll
  for (int it = 0; it < 2; ++it) {
    int e = it * 512 + tid, r = e >> 3, c = e & 7, sc = c ^ (r & 7);
    __builtin_amdgcn_global_load_lds(
        (const __attribute__((address_space(1))) unsigned int*)(Qi + (size_t)(row0 + r) * 64 + sc * 8),
        (__attribute__((address_space(3))) unsigned int*)(smA + r * 64 + c * 8), 16, 0, 0);
  }
#pragma unroll
  for (int it = 0; it < 4; ++it) {
    int e = it * 512 + tid, r = e >> 3, c = e & 7, sc = c ^ (r & 7);
    __builtin_amdgcn_global_load_lds(
        (const __attribute__((address_space(1))) unsigned int*)(Ki + (size_t)(col0 + r) * 64 + sc * 8),
        (__attribute__((address_space(3))) unsigned int*)(smB + r * 64 + c * 8), 16, 0, 0);
  }
  __syncthreads();

  // ---- MFMA: per wave 64x64, FM=4 FN=4, 2 ksteps ----
  const int lr = lane & 15, kq = lane >> 4;
  f32x4 acc[4][4] = {};
#pragma unroll
  for (int kk = 0; kk < 2; ++kk) {
    const int ch = (kk * 4 + kq) ^ (lr & 7);
    f16x8 av[4], bv[4];
#pragma unroll
    for (int i = 0; i < 4; ++i)
      av[i] = *reinterpret_cast<const f16x8*>(&smA[(wr * 64 + i * 16 + lr) * 64 + ch * 8]);
#pragma unroll
    for (int j = 0; j < 4; ++j)
      bv[j] = *reinterpret_cast<const f16x8*>(&smB[(wc * 64 + j * 16 + lr) * 64 + ch * 8]);
#pragma unroll
    for (int i = 0; i < 4; ++i)
#pragma unroll
      for (int j = 0; j < 4; ++j)
        acc[i][j] = __builtin_amdgcn_mfma_f32_16x16x32_f16(av[i], bv[j], acc[i][j], 0, 0, 0);
  }
  __syncthreads();   // stage LDS dead; safe to overwrite with Dt

  // ---- write Dt[m][n] (transposed), 8B vector writes ----
#pragma unroll
  for (int i = 0; i < 4; ++i) {
    int n0 = wr * 64 + i * 16 + kq * 4;
#pragma unroll
    for (int j = 0; j < 4; ++j) {
      int m = wc * 64 + j * 16 + lr;
      ushort4 o4;
      o4.x = f2h_bits(acc[i][j][0]); o4.y = f2h_bits(acc[i][j][1]);
      o4.z = f2h_bits(acc[i][j][2]); o4.w = f2h_bits(acc[i][j][3]);
      *reinterpret_cast<ushort4*>(Dt + m * NP + n0) = o4;
    }
  }
  __syncthreads();

  // ---- conv + transpose + coalesced writeout ----
  // thread decomposition: w2i = tid>>7 (0..3), b_=(tid>>4)&7, a_=(tid>>2)&3, w1q=(tid&3)*8
  const int w2i = tid >> 7;
  const int b_  = (tid >> 4) & 7;
  const int a_  = (tid >> 2) & 3;
  const int w1q = (tid & 3) * 8;
  const int cch = (bx * 4 + a_) * 32 + (by * 8 + b_);     // true channel
  const float u0 = wc1[2 * cch], u1 = wc1[2 * cch + 1];   // conv along w2
  const float v0 = wc2[2 * cch], v1 = wc2[2 * cch + 1];   // conv along w1
  const int cblk = (bx * 4 + by) * 32;                    // c' base
  __half* ACi = AC + ((size_t)img << 20);
  const int w1o = (tid >> 2) & 31, ck = tid & 3;          // writeout mapping

  for (int pass = 0; pass < 8; ++pass) {
    const int w2 = pass * 4 + w2i;
    const int w2n = (w2 < 31) ? w2 + 1 : 30;              // reflect right
    const __half* r0 = Dt + (b_ * 32 + w2) * NP + a_ * 32 + w1q;
    const __half* r1 = Dt + (b_ * 32 + w2n) * NP + a_ * 32 + w1q;
    float X[9];
    {
      ushort4 x0a = *reinterpret_cast<const ushort4*>(r0);
      ushort4 x0b = *reinterpret_cast<const ushort4*>(r0 + 4);
      ushort4 x1a = *reinterpret_cast<const ushort4*>(r1);
      ushort4 x1b = *reinterpret_cast<const ushort4*>(r1 + 4);
      X[0] = u0 * h2f_bits(x0a.x) + u1 * h2f_bits(x1a.x);
      X[1] = u0 * h2f_bits(x0a.y) + u1 * h2f_bits(x1a.y);
      X[2] = u0 * h2f_bits(x0a.z) + u1 * h2f_bits(x1a.z);
      X[3] = u0 * h2f_bits(x0a.w) + u1 * h2f_bits(x1a.w);
      X[4] = u0 * h2f_bits(x0b.x) + u1 * h2f_bits(x1b.x);
      X[5] = u0 * h2f_bits(x0b.y) + u1 * h2f_bits(x1b.y);
      X[6] = u0 * h2f_bits(x0b.z) + u1 * h2f_bits(x1b.z);
      X[7] = u0 * h2f_bits(x0b.w) + u1 * h2f_bits(x1b.w);
      X[8] = u0 * __half2float(r0[8]) + u1 * __half2float(r1[8]);  // pad-safe, unused at w1q=24
    }
#pragma unroll
    for (int k = 0; k < 8; ++k) {
      float ov = (w1q + k < 31) ? (v0 * X[k] + v1 * X[k + 1])
                                : (v0 * X[7] + v1 * X[6]);        // reflect bottom (w1=31)
      T[(w2i * 32 + w1q + k) * 40 + a_ * 8 + b_] = __float2half(ov);
    }
    __syncthreads();
    {
      const int w2o = pass * 4 + (tid >> 7);
      u16x8 v = *reinterpret_cast<const u16x8*>(T + ((tid >> 7) * 32 + w1o) * 40 + ck * 8);
      *reinterpret_cast<u16x8*>(ACi + (size_t)(w1o * 32 + w2o) * 1024 + cblk + ck * 8) = v;
    }
    __syncthreads();
  }
}

// ---------------- 256x256-tile 8-wave GEMM for the 1x1 conv (+BN+SiLU+softmax) ----------------
// (round-6 form: 2-slot dbuf, phased staging, __syncthreads per iter — best measured)
struct Epi1x1F8 {
  __half* P;
  const float *g, *b, *m, *vv;
  DEV void finalize(int img, int ob, int cb, int lane, f32x4 (&acc)[8][4]) const {
    const int lr = lane & 15, kq = lane >> 4;
    __half* Pi = P + ((size_t)img << 20);
#pragma unroll
    for (int ih = 0; ih < 4; ++ih) {
#pragma unroll
      for (int sh = 0; sh < 2; ++sh) {
        float v[2][2][4];
        float mx = -1e30f;
#pragma unroll
        for (int di = 0; di < 2; ++di) {
          int i = ih * 2 + di;
#pragma unroll
          for (int q = 0; q < 4; ++q) {
            int o = ob + i * 16 + kq * 4 + q;
            float sc = rsqrtf(vv[o] + 1e-5f) * g[o];
            float mo = m[o], bo = b[o];
#pragma unroll
            for (int dj = 0; dj < 2; ++dj) {
              float t = (acc[i][sh * 2 + dj][q] - mo) * sc + bo;
              t = t / (1.f + __expf(-t));       // SiLU
              v[di][dj][q] = t;
              mx = fmaxf(mx, t);
            }
          }
        }
#pragma unroll
        for (int off = 32; off; off >>= 1) mx = fmaxf(mx, __shfl_xor(mx, off));
        float sm = 0.f;
#pragma unroll
        for (int di = 0; di < 2; ++di)
#pragma unroll
          for (int dj = 0; dj < 2; ++dj)
#pragma unroll
            for (int q = 0; q < 4; ++q) {
              float e = __expf(v[di][dj][q] - mx);
              v[di][dj][q] = e; sm += e;
            }
#pragma unroll
        for (int off = 32; off; off >>= 1) sm += __shfl_xor(sm, off);
        float inv = 1.f / sm;
#pragma unroll
        for (int di = 0; di < 2; ++di) {
          int i = ih * 2 + di;
#pragma unroll
          for (int q = 0; q < 4; ++q) {
            int o = ob + i * 16 + kq * 4 + q;
            size_t nhi = (size_t)(o >> 5) * 32;
            int mlo = (o & 31) * 32;
#pragma unroll
            for (int dj = 0; dj < 2; ++dj) {
              int s = cb + (sh * 2 + dj) * 16 + lr;
              Pi[(nhi + (s >> 5)) * 1024 + mlo + (s & 31)] = __float2half(v[di][dj][q] * inv);
            }
          }
        }
      }
    }
  }
};

template <class Epi>
__global__ __launch_bounds__(512, 1) void gemm8(
    const __half* __restrict__ A, long long aStride,
    const __half* __restrict__ B, long long bStride,
    int K, Epi epi) {
  __shared__ __align__(16) __half smA[2][256 * 32];
  __shared__ __align__(16) __half smB[2][256 * 32];
  const int tid = threadIdx.x;
  const int lane = tid & 63, wid = tid >> 6;
  const int wr = wid >> 2, wc = wid & 3;
  const int gx = gridDim.x, gxy = gx * gridDim.y;
  const int nwg = gxy * gridDim.z;
  const int b_lin = blockIdx.x + blockIdx.y * gx + blockIdx.z * gxy;
  const int logical = (b_lin & 7) * (nwg >> 3) + (b_lin >> 3);
  const int bx = logical % gx, by = (logical / gx) % gridDim.y, bz = logical / gxy;
  const int img = bz, row0 = bx * 256, col0 = by * 256;
  const __half* Ab = A + (size_t)((long long)img * aStride);
  const __half* Bb = B + (size_t)((long long)img * bStride);

  const int tau = tid & 255;
  const bool grpB = (tid >= 256);
  const __half* Mb = grpB ? Bb : Ab;
  const int rc0 = grpB ? col0 : row0;
  const int cch = tau & 3;
  const int swc = cch ^ ((tau >> 3) & 3);
  const __half* pg[4]; int dstoff[4];
#pragma unroll
  for (int s = 0; s < 4; ++s) {
    int r = (tau >> 2) + 64 * s;
    pg[s] = Mb + (size_t)(rc0 + r) * K + swc * 8;
    dstoff[s] = r * 32 + cch * 8;
  }
  __half* smDst = grpB ? &smB[0][0] : &smA[0][0];
  auto stage1 = [&](int buf, int kt, int s) {
    __builtin_amdgcn_global_load_lds(
        (const __attribute__((address_space(1))) unsigned int*)(pg[s] + kt),
        (__attribute__((address_space(3))) unsigned int*)(smDst + buf * 8192 + dstoff[s]),
        16, 0, 0);
  };

  const int lr = lane & 15, kq = lane >> 4;
  const int ch = kq ^ ((lr >> 1) & 3);
  const int aOff = (wr * 128 + lr) * 32 + ch * 8;
  const int bOff = (wc * 64 + lr) * 32 + ch * 8;
  f32x4 acc[8][4] = {};

  const int NT = K / 32;
  stage1(0, 0, 0); stage1(0, 0, 1); stage1(0, 0, 2); stage1(0, 0, 3);
  __syncthreads();
  int cur = 0;
  for (int t = 0; t < NT; ++t) {
    const int ktn = (t + 1) * 32;
    const bool pf = (t + 1) < NT;
    const __half* sA = &smA[cur][0];
    const __half* sB = &smB[cur][0];
    const int nb = cur ^ 1;
    f16x8 bv[4];
    if (pf) { stage1(nb, ktn, 0); stage1(nb, ktn, 1); }
#pragma unroll
    for (int j = 0; j < 4; ++j) bv[j] = *reinterpret_cast<const f16x8*>(&sB[bOff + j * 512]);
    {
      f16x8 a0 = *reinterpret_cast<const f16x8*>(&sA[aOff + 0 * 512]);
      f16x8 a1 = *reinterpret_cast<const f16x8*>(&sA[aOff + 1 * 512]);
      __builtin_amdgcn_s_setprio(1);
#pragma unroll
      for (int j = 0; j < 4; ++j) acc[0][j] = __builtin_amdgcn_mfma_f32_16x16x32_f16(a0, bv[j], acc[0][j], 0, 0, 0);
#pragma unroll
      for (int j = 0; j < 4; ++j) acc[1][j] = __builtin_amdgcn_mfma_f32_16x16x32_f16(a1, bv[j], acc[1][j], 0, 0, 0);
      __builtin_amdgcn_s_setprio(0);
    }
    if (pf) { stage1(nb, ktn, 2); stage1(nb, ktn, 3); }
    {
      f16x8 a0 = *reinterpret_cast<const f16x8*>(&sA[aOff + 2 * 512]);
      f16x8 a1 = *reinterpret_cast<const f16x8*>(&sA[aOff + 3 * 512]);
      __builtin_amdgcn_s_setprio(1);
#pragma unroll
      for (int j = 0; j < 4; ++j) acc[2][j] = __builtin_amdgcn_mfma_f32_16x16x32_f16(a0, bv[j], acc[2][j], 0, 0, 0);
#pragma unroll
      for (int j = 0; j < 4; ++j) acc[3][j] = __builtin_amdgcn_mfma_f32_16x16x32_f16(a1, bv[j], acc[3][j], 0, 0, 0);
      __builtin_amdgcn_s_setprio(0);
    }
    {
      f16x8 a0 = *reinterpret_cast<const f16x8*>(&sA[aOff + 4 * 512]);
      f16x8 a1 = *reinterpret_cast<const f16x8*>(&sA[aOff + 5 * 512]);
      __builtin_amdgcn_s_setprio(1);
#pragma unroll
      for (int j = 0; j < 4; ++j) acc[4][j] = __builtin_amdgcn_mfma_f32_16x16x32_f16(a0, bv[j], acc[4][j], 0, 0, 0);
#pragma unroll
      for (int j = 0; j < 4; ++j) acc[5][j] = __builtin_amdgcn_mfma_f32_16x16x32_f16(a1, bv[j], acc[5][j], 0, 0, 0);
      __builtin_amdgcn_s_setprio(0);
    }
    {
      f16x8 a0 = *reinterpret_cast<const f16x8*>(&sA[aOff + 6 * 512]);
      f16x8 a1 = *reinterpret_cast<const f16x8*>(&sA[aOff + 7 * 512]);
      __builtin_amdgcn_s_setprio(1);
#pragma unroll
      for (int j = 0; j < 4; ++j) acc[6][j] = __builtin_amdgcn_mfma_f32_16x16x32_f16(a0, bv[j], acc[6][j], 0, 0, 0);
#pragma unroll
      for (int j = 0; j < 4; ++j) acc[7][j] = __builtin_amdgcn_mfma_f32_16x16x32_f16(a1, bv[j], acc[7][j], 0, 0, 0);
      __builtin_amdgcn_s_setprio(0);
    }
    __syncthreads();
    cur ^= 1;
  }
  epi.finalize(img, row0 + wr * 128, col0 + wc * 64, lane, acc);
}

extern "C" void kernel_launch(void* const* d_in, const int* in_sizes, int n_in,
                              void* d_out, int out_size, void* d_ws, size_t ws_size,
                              hipStream_t stream) {
  const float* x     = (const float*)d_in[0];
  const float* ln_g  = (const float*)d_in[1];
  const float* ln_b  = (const float*)d_in[2];
  const float* w_qkv = (const float*)d_in[3];
  const float* wc1   = (const float*)d_in[4];
  const float* wc2   = (const float*)d_in[5];
  const float* w1x1  = (const float*)d_in[6];
  const float* bn_g  = (const float*)d_in[7];
  const float* bn_b  = (const float*)d_in[8];
  const float* bn_m  = (const float*)d_in[9];
  const float* bn_v  = (const float*)d_in[10];
  const float* w_out = (const float*)d_in[11];
  const float* b_out = (const float*)d_in[12];
  float* out = (float*)d_out;

  const size_t MB = 1024 * 1024;
  char* ws = (char*)d_ws;
  // region0 (64MB): P (fused 1x1 output)
  __half* Pb = (__half*)ws;
  // region1 (64MB): AC (fused QK+conv output, permuted channels)
  __half* ACb = (__half*)(ws + 64 * MB);
  // statics
  char* p = ws + 128 * MB;
  __half* XN    = (__half*)p; p += 2 * MB;            // 4096x256
  __half* WQKVT = (__half*)p; p += 1536 * 256 * 2;    // 1536x256
  __half* W1X1H = (__half*)p; p += 2 * MB;            // 1024x1024 (K permuted)
  __half* WOTT  = (__half*)p; p += 256 * 512 * 2;     // 256x512
  __half* Qb    = (__half*)p; p += 4 * MB;            // 32x1024x64 (scaled)
  __half* Kb    = (__half*)p; p += 4 * MB;            // 32x1024x64
  __half* Vtb   = (__half*)p; p += 4 * MB;            // 32x64x1024
  __half* Ob    = (__half*)p; p += 4 * MB;            // 4096x512

  prep_kernel<<<2048, 256, 0, stream>>>(w_qkv, w1x1, w_out, WQKVT, W1X1H, WOTT);
  ln_kernel<<<4096, 256, 0, stream>>>(x, ln_g, ln_b, XN);

  { EpiQKV e{Qb, Kb, Vtb};
    gemm_bt<128, 128, 64, 2, 4, 4, EpiQKV><<<dim3(32, 12, 1), 256, 0, stream>>>(
        XN, 0, WQKVT, 0, 256, e); }

  qkconv_kernel<<<dim3(8, 4, 32), 512, 0, stream>>>(Qb, Kb, wc1, wc2, ACb);

  { Epi1x1F8 e{Pb, bn_g, bn_b, bn_m, bn_v};
    gemm8<Epi1x1F8><<<dim3(4, 4, 32), 512, 0, stream>>>(
        W1X1H, 0, ACb, 1 << 20, 1024, e); }

  { EpiPV e{Ob};
    gemm_bt<64, 64, 64, 2, 2, 2, EpiPV><<<dim3(16, 1, 32), 256, 0, stream>>>(
        Pb, 1 << 20, Vtb, 65536, 1024, e); }

  { EpiOut e{out, b_out};
    gemm_bt<128, 128, 64, 2, 4, 4, EpiOut><<<dim3(32, 2, 1), 256, 0, stream>>>(
        Ob, 0, WOTT, 0, 512, e); }
}

// Round 10
// 184.481 us; speedup vs baseline: 1.2358x; 1.0657x over previous
//
#include <hip/hip_runtime.h>
#include <hip/hip_fp16.h>

// AttentionQV0: LN -> QKV -> [QK^T + dw-convs fused] -> 1x1 conv+BN+SiLU+softmax(fused) -> PV -> out proj
// B=2,P=2,N=1024,DIM=256,HEADS=8,DH=64,HW=32,C=1024. 32 "images" of 1024x1024 scores.
// D (QK scores) never hits HBM: conv runs in the QK epilogue from LDS.
// AC uses a permuted channel axis c' = (bx*4+by)*32 + a*8 + b; W1X1H K-permuted to match.
// 1x1 GEMM: 128x128-tile 8-wave kernel, acc[4][2]=32 AGPR -> <=128 unified regs
// (launch_bounds(512,4)) -> 4 waves/SIMD -> 2 blocks/CU co-resident (cross-block TLP
// hides barrier drains; the 256^2 8-wave version was reg-capped at 1 block/CU).

#define DEV __device__ __forceinline__

typedef __attribute__((ext_vector_type(8))) _Float16 f16x8;
typedef __attribute__((ext_vector_type(4))) float f32x4;
typedef __attribute__((ext_vector_type(8))) unsigned short u16x8;

DEV float h2f_bits(unsigned short u) { __half h; *reinterpret_cast<unsigned short*>(&h) = u; return __half2float(h); }
DEV unsigned short f2h_bits(float f) { __half h = __float2half(f); return *reinterpret_cast<unsigned short*>(&h); }

// ---------------- prep: cast/transpose weights to f16 ----------------
__global__ __launch_bounds__(256) void prep_kernel(
    const float* __restrict__ wqkv, const float* __restrict__ w1x1,
    const float* __restrict__ wout,
    __half* __restrict__ WQKVT, __half* __restrict__ W1X1H, __half* __restrict__ WOTT) {
  int i0 = blockIdx.x * 256 + threadIdx.x;
  int stride = gridDim.x * 256;
  for (int i = i0; i < 1536 * 256; i += stride) {          // WQKVT[j][k] = wqkv[k][j]
    int j = i >> 8, k = i & 255;
    WQKVT[i] = __float2half(wqkv[k * 1536 + j]);
  }
  for (int i = i0; i < 1024 * 1024; i += stride) {         // permuted K axis: col p -> c(p)
    int o = i >> 10, p = i & 1023;
    int blk = p >> 5, r = p & 31, a = r >> 3, bb = r & 7;
    int h1 = (blk >> 2) * 4 + a, h2 = (blk & 3) * 8 + bb;
    W1X1H[i] = __float2half(w1x1[o * 1024 + h1 * 32 + h2]);
  }
  for (int i = i0; i < 256 * 512; i += stride) {           // WOTT[j][k] = wout[k][j]
    int j = i >> 9, k = i & 511;
    WOTT[i] = __float2half(wout[k * 256 + j]);
  }
}

// ---------------- LayerNorm (row = token, 256 threads) ----------------
__global__ __launch_bounds__(256) void ln_kernel(const float* __restrict__ x,
    const float* __restrict__ g, const float* __restrict__ b, __half* __restrict__ XN) {
  int row = blockIdx.x;
  int tid = threadIdx.x, lane = tid & 63, wid = tid >> 6;
  float xv = x[(size_t)row * 256 + tid];
  float s = xv, q = xv * xv;
#pragma unroll
  for (int off = 32; off; off >>= 1) { s += __shfl_xor(s, off); q += __shfl_xor(q, off); }
  __shared__ float rs[4], rq[4];
  if (lane == 0) { rs[wid] = s; rq[wid] = q; }
  __syncthreads();
  s = rs[0] + rs[1] + rs[2] + rs[3];
  q = rq[0] + rq[1] + rq[2] + rq[3];
  float mu = s * (1.f / 256.f);
  float var = q * (1.f / 256.f) - mu * mu;
  float r = rsqrtf(var + 1e-5f);
  XN[(size_t)row * 256 + tid] = __float2half((xv - mu) * r * g[tid] + b[tid]);
}

// ---------------- generic BT GEMM (4 waves): QKV / PV / out ----------------
template <int BM, int BN, int BK, int WGN, int FM, int FN, class Epi>
__global__ __launch_bounds__(256) void gemm_bt(
    const __half* __restrict__ A, long long aStride,
    const __half* __restrict__ B, long long bStride,
    int K, Epi epi) {
  constexpr int CPR = BK / 8;                 // 16B chunks per row
  constexpr int NCA = (BM * BK) / (8 * 256);
  constexpr int NCB = (BN * BK) / (8 * 256);
  constexpr int KSUB = BK / 32;               // mfma k-steps per tile
  __shared__ __align__(16) __half smA[2][BM * BK];
  __shared__ __align__(16) __half smB[2][BN * BK];
  const int tid = threadIdx.x;
  const int lane = tid & 63, wid = tid >> 6;
  const int wr = wid / WGN, wc = wid % WGN;
  const int gx = gridDim.x, gxy = gridDim.x * gridDim.y;
  const int nwg = gxy * gridDim.z;
  const int b_lin = blockIdx.x + blockIdx.y * gx + blockIdx.z * gxy;
  const int logical = (b_lin & 7) * (nwg >> 3) + (b_lin >> 3);
  const int bx = logical % gx, by = (logical / gx) % gridDim.y, bz = logical / gxy;
  const int img = bz;
  const int row0 = bx * BM;
  const int col0 = by * BN;
  const __half* Ab = A + (size_t)((long long)img * aStride);
  const __half* Bb = B + (size_t)((long long)img * bStride);
  f32x4 acc[FM][FN] = {};
  const int lr = lane & 15;
  const int kq = lane >> 4;                   // 0..3 (16B chunk within k-sub)

  auto swz = [](int c, int r) -> int {
    return (CPR == 8) ? (c ^ (r & 7)) : (c ^ ((r >> 1) & 3));
  };

  const __half* pA[NCA]; int dA[NCA];
  const __half* pB[NCB]; int dB[NCB];
#pragma unroll
  for (int it = 0; it < NCA; ++it) {
    int e = it * 256 + tid, r = e / CPR, c = e % CPR;
    pA[it] = Ab + (size_t)(row0 + r) * K + swz(c, r) * 8;
    dA[it] = r * BK + c * 8;
  }
#pragma unroll
  for (int it = 0; it < NCB; ++it) {
    int e = it * 256 + tid, r = e / CPR, c = e % CPR;
    pB[it] = Bb + (size_t)(col0 + r) * K + swz(c, r) * 8;
    dB[it] = r * BK + c * 8;
  }

  auto stage = [&](int buf, int kt) {
#pragma unroll
    for (int it = 0; it < NCA; ++it)
      __builtin_amdgcn_global_load_lds(
          (const __attribute__((address_space(1))) unsigned int*)(pA[it] + kt),
          (__attribute__((address_space(3))) unsigned int*)(&smA[buf][dA[it]]),
          16, 0, 0);
#pragma unroll
    for (int it = 0; it < NCB; ++it)
      __builtin_amdgcn_global_load_lds(
          (const __attribute__((address_space(1))) unsigned int*)(pB[it] + kt),
          (__attribute__((address_space(3))) unsigned int*)(&smB[buf][dB[it]]),
          16, 0, 0);
  };

  const int NT = K / BK;
  stage(0, 0);
  __syncthreads();
  int cur = 0;
  for (int t = 0; t < NT; ++t) {
    if (t + 1 < NT) stage(cur ^ 1, (t + 1) * BK);   // prefetch next tile first
#pragma unroll
    for (int kk = 0; kk < KSUB; ++kk) {
      f16x8 av[FM], bv[FN];
#pragma unroll
      for (int i = 0; i < FM; ++i) {
        int row = wr * FM * 16 + i * 16 + lr;
        int ch = swz(kk * 4 + kq, lr);
        av[i] = *reinterpret_cast<const f16x8*>(&smA[cur][row * BK + ch * 8]);
      }
#pragma unroll
      for (int j = 0; j < FN; ++j) {
        int row = wc * FN * 16 + j * 16 + lr;
        int ch = swz(kk * 4 + kq, lr);
        bv[j] = *reinterpret_cast<const f16x8*>(&smB[cur][row * BK + ch * 8]);
      }
#pragma unroll
      for (int i = 0; i < FM; ++i)
#pragma unroll
        for (int j = 0; j < FN; ++j)
          acc[i][j] = __builtin_amdgcn_mfma_f32_16x16x32_f16(av[i], bv[j], acc[i][j], 0, 0, 0);
    }
    __syncthreads();
    cur ^= 1;
  }

  const int orow = row0 + wr * FM * 16 + (lane >> 4) * 4;
  const int ocol = col0 + wc * FN * 16 + lr;
#pragma unroll
  for (int i = 0; i < FM; ++i)
#pragma unroll
    for (int j = 0; j < FN; ++j)
#pragma unroll
      for (int q = 0; q < 4; ++q)
        epi.store(img, orow + i * 16 + q, ocol + j * 16, acc[i][j][q]);
}

// ---------------- epilogues ----------------
struct EpiQKV {  // rows t in [0,4096), cols j in [0,1536)
  __half *Q, *K, *V;
  DEV void store(int, int t, int j, float v) const {
    int part = j >> 9, inner = j & 511;
    int h = inner >> 6, d = inner & 63;
    int bp = t >> 10, n = t & 1023;
    size_t img = (size_t)(bp * 8 + h);
    if (part == 0)       Q[(img * 1024 + n) * 64 + d] = __float2half(v * 0.125f); // fold DH^-0.5
    else if (part == 1)  K[(img * 1024 + n) * 64 + d] = __float2half(v);
    else                 V[(img * 64 + d) * 1024 + n] = __float2half(v);          // V transposed
  }
};
struct EpiPV {   // rows n, cols d -> O[(bp*1024+n)][h*64+d]
  __half* O;
  DEV void store(int img, int n, int d, float v) const {
    int bp = img >> 3, h = img & 7;
    O[((size_t)(bp * 1024 + n)) * 512 + h * 64 + d] = __float2half(v);
  }
};
struct EpiOut {  // rows t, cols j -> out f32 + bias
  float* out; const float* bias;
  DEV void store(int, int t, int j, float v) const {
    out[(size_t)t * 256 + j] = v + bias[j];
  }
};

// ---------------- fused QK^T + depthwise convs ----------------
__global__ __launch_bounds__(512) void qkconv_kernel(
    const __half* __restrict__ Q, const __half* __restrict__ Km,
    const float* __restrict__ wc1, const float* __restrict__ wc2,
    __half* __restrict__ AC) {
  constexpr int NP = 132;                       // Dt inner pad (halfs)
  __shared__ __align__(16) char LDS[77824];     // max(stage 48K, Dt 66K) + T 10K
  __half* smA = (__half*)LDS;                   // [128][64]  16384 B
  __half* smB = (__half*)(LDS + 16384);         // [256][64]  32768 B
  __half* Dt  = (__half*)LDS;                   // [256][132] 67584 B (aliases stage)
  __half* T   = (__half*)(LDS + 67584);         // [4][32][40] 10240 B
  const int tid = threadIdx.x;
  const int lane = tid & 63, wid = tid >> 6;
  const int wr = wid >> 2, wc = wid & 3;
  // XCD swizzle, grid 8 x 4 x 32 = 1024 (%8==0)
  const int gx = gridDim.x, gxy = gx * gridDim.y;
  const int nwg = gxy * gridDim.z;
  const int b_lin = blockIdx.x + blockIdx.y * gx + blockIdx.z * gxy;
  const int logical = (b_lin & 7) * (nwg >> 3) + (b_lin >> 3);
  const int bx = logical % gx, by = (logical / gx) % gridDim.y, bz = logical / gxy;
  const int img = bz, row0 = bx * 128, col0 = by * 256;
  const __half* Qi = Q + ((size_t)img << 16);
  const __half* Ki = Km + ((size_t)img << 16);

#pragma unroll
  for (int it = 0; it < 2; ++it) {
    int e = it * 512 + tid, r = e >> 3, c = e & 7, sc = c ^ (r & 7);
    __builtin_amdgcn_global_load_lds(
        (const __attribute__((address_space(1))) unsigned int*)(Qi + (size_t)(row0 + r) * 64 + sc * 8),
        (__attribute__((address_space(3))) unsigned int*)(smA + r * 64 + c * 8), 16, 0, 0);
  }
#pragma unroll
  for (int it = 0; it < 4; ++it) {
    int e = it * 512 + tid, r = e >> 3, c = e & 7, sc = c ^ (r & 7);
    __builtin_amdgcn_global_load_lds(
        (const __attribute__((address_space(1))) unsigned int*)(Ki + (size_t)(col0 + r) * 64 + sc * 8),
        (__attribute__((address_space(3))) unsigned int*)(smB + r * 64 + c * 8), 16, 0, 0);
  }
  __syncthreads();

  const int lr = lane & 15, kq = lane >> 4;
  f32x4 acc[4][4] = {};
#pragma unroll
  for (int kk = 0; kk < 2; ++kk) {
    const int ch = (kk * 4 + kq) ^ (lr & 7);
    f16x8 av[4], bv[4];
#pragma unroll
    for (int i = 0; i < 4; ++i)
      av[i] = *reinterpret_cast<const f16x8*>(&smA[(wr * 64 + i * 16 + lr) * 64 + ch * 8]);
#pragma unroll
    for (int j = 0; j < 4; ++j)
      bv[j] = *reinterpret_cast<const f16x8*>(&smB[(wc * 64 + j * 16 + lr) * 64 + ch * 8]);
#pragma unroll
    for (int i = 0; i < 4; ++i)
#pragma unroll
      for (int j = 0; j < 4; ++j)
        acc[i][j] = __builtin_amdgcn_mfma_f32_16x16x32_f16(av[i], bv[j], acc[i][j], 0, 0, 0);
  }
  __syncthreads();   // stage LDS dead; safe to overwrite with Dt

#pragma unroll
  for (int i = 0; i < 4; ++i) {
    int n0 = wr * 64 + i * 16 + kq * 4;
#pragma unroll
    for (int j = 0; j < 4; ++j) {
      int m = wc * 64 + j * 16 + lr;
      ushort4 o4;
      o4.x = f2h_bits(acc[i][j][0]); o4.y = f2h_bits(acc[i][j][1]);
      o4.z = f2h_bits(acc[i][j][2]); o4.w = f2h_bits(acc[i][j][3]);
      *reinterpret_cast<ushort4*>(Dt + m * NP + n0) = o4;
    }
  }
  __syncthreads();

  const int w2i = tid >> 7;
  const int b_  = (tid >> 4) & 7;
  const int a_  = (tid >> 2) & 3;
  const int w1q = (tid & 3) * 8;
  const int cch = (bx * 4 + a_) * 32 + (by * 8 + b_);
  const float u0 = wc1[2 * cch], u1 = wc1[2 * cch + 1];
  const float v0 = wc2[2 * cch], v1 = wc2[2 * cch + 1];
  const int cblk = (bx * 4 + by) * 32;
  __half* ACi = AC + ((size_t)img << 20);
  const int w1o = (tid >> 2) & 31, ck = tid & 3;

  for (int pass = 0; pass < 8; ++pass) {
    const int w2 = pass * 4 + w2i;
    const int w2n = (w2 < 31) ? w2 + 1 : 30;
    const __half* r0 = Dt + (b_ * 32 + w2) * NP + a_ * 32 + w1q;
    const __half* r1 = Dt + (b_ * 32 + w2n) * NP + a_ * 32 + w1q;
    float X[9];
    {
      ushort4 x0a = *reinterpret_cast<const ushort4*>(r0);
      ushort4 x0b = *reinterpret_cast<const ushort4*>(r0 + 4);
      ushort4 x1a = *reinterpret_cast<const ushort4*>(r1);
      ushort4 x1b = *reinterpret_cast<const ushort4*>(r1 + 4);
      X[0] = u0 * h2f_bits(x0a.x) + u1 * h2f_bits(x1a.x);
      X[1] = u0 * h2f_bits(x0a.y) + u1 * h2f_bits(x1a.y);
      X[2] = u0 * h2f_bits(x0a.z) + u1 * h2f_bits(x1a.z);
      X[3] = u0 * h2f_bits(x0a.w) + u1 * h2f_bits(x1a.w);
      X[4] = u0 * h2f_bits(x0b.x) + u1 * h2f_bits(x1b.x);
      X[5] = u0 * h2f_bits(x0b.y) + u1 * h2f_bits(x1b.y);
      X[6] = u0 * h2f_bits(x0b.z) + u1 * h2f_bits(x1b.z);
      X[7] = u0 * h2f_bits(x0b.w) + u1 * h2f_bits(x1b.w);
      X[8] = u0 * __half2float(r0[8]) + u1 * __half2float(r1[8]);
    }
#pragma unroll
    for (int k = 0; k < 8; ++k) {
      float ov = (w1q + k < 31) ? (v0 * X[k] + v1 * X[k + 1])
                                : (v0 * X[7] + v1 * X[6]);
      T[(w2i * 32 + w1q + k) * 40 + a_ * 8 + b_] = __float2half(ov);
    }
    __syncthreads();
    {
      const int w2o = pass * 4 + (tid >> 7);
      u16x8 v = *reinterpret_cast<const u16x8*>(T + ((tid >> 7) * 32 + w1o) * 40 + ck * 8);
      *reinterpret_cast<u16x8*>(ACi + (size_t)(w1o * 32 + w2o) * 1024 + cblk + ck * 8) = v;
    }
    __syncthreads();
  }
}

// ---------------- 128x128-tile 8-wave GEMM for the 1x1 conv (+BN+SiLU+softmax) ----------------
// Per wave 64x32 (acc[4][2]=32 AGPR). launch_bounds(512,4) caps regs at 128 ->
// 4 waves/SIMD -> 2 blocks/CU co-resident. LDS 32KB/slot dbuf = 64KB/block.
struct Epi1x1S {
  __half* P;
  const float *g, *b, *m, *vv;
  // ob = row0 + wr*64 (o base), cb = col0 + wc*32 (s base)
  DEV void finalize(int img, int ob, int cb, int lane, f32x4 (&acc)[4][2]) const {
    const int lr = lane & 15, kq = lane >> 4;
    __half* Pi = P + ((size_t)img << 20);
#pragma unroll
    for (int ih = 0; ih < 2; ++ih) {           // two 32-row o-groups; one s-group (32 cols)
      float v[2][2][4];
      float mx = -1e30f;
#pragma unroll
      for (int di = 0; di < 2; ++di) {
        int i = ih * 2 + di;
#pragma unroll
        for (int q = 0; q < 4; ++q) {
          int o = ob + i * 16 + kq * 4 + q;
          float sc = rsqrtf(vv[o] + 1e-5f) * g[o];
          float mo = m[o], bo = b[o];
#pragma unroll
          for (int dj = 0; dj < 2; ++dj) {
            float t = (acc[i][dj][q] - mo) * sc + bo;
            t = t / (1.f + __expf(-t));       // SiLU
            v[di][dj][q] = t;
            mx = fmaxf(mx, t);
          }
        }
      }
#pragma unroll
      for (int off = 32; off; off >>= 1) mx = fmaxf(mx, __shfl_xor(mx, off));
      float sm = 0.f;
#pragma unroll
      for (int di = 0; di < 2; ++di)
#pragma unroll
        for (int dj = 0; dj < 2; ++dj)
#pragma unroll
          for (int q = 0; q < 4; ++q) {
            float e = __expf(v[di][dj][q] - mx);
            v[di][dj][q] = e; sm += e;
          }
#pragma unroll
      for (int off = 32; off; off >>= 1) sm += __shfl_xor(sm, off);
      float inv = 1.f / sm;
#pragma unroll
      for (int di = 0; di < 2; ++di) {
        int i = ih * 2 + di;
#pragma unroll
        for (int q = 0; q < 4; ++q) {
          int o = ob + i * 16 + kq * 4 + q;
          size_t nhi = (size_t)(o >> 5) * 32;
          int mlo = (o & 31) * 32;
#pragma unroll
          for (int dj = 0; dj < 2; ++dj) {
            int s = cb + dj * 16 + lr;
            Pi[(nhi + (s >> 5)) * 1024 + mlo + (s & 31)] = __float2half(v[di][dj][q] * inv);
          }
        }
      }
    }
  }
};

template <class Epi>
__global__ __launch_bounds__(512, 4) void gemm1x1(
    const __half* __restrict__ A,
    const __half* __restrict__ B, long long bStride,
    int K, Epi epi) {
  __shared__ __align__(16) __half smA[2][128 * 64];
  __shared__ __align__(16) __half smB[2][128 * 64];
  const int tid = threadIdx.x;
  const int lane = tid & 63, wid = tid >> 6;
  const int wr = wid >> 2, wc = wid & 3;      // 2 x 4 waves; wave tile 64x32
  // XCD swizzle (nwg = 2048, %8==0)
  const int gx = gridDim.x, gxy = gx * gridDim.y;
  const int nwg = gxy * gridDim.z;
  const int b_lin = blockIdx.x + blockIdx.y * gx + blockIdx.z * gxy;
  const int logical = (b_lin & 7) * (nwg >> 3) + (b_lin >> 3);
  const int bx = logical % gx, by = (logical / gx) % gridDim.y, bz = logical / gxy;
  const int img = bz, row0 = bx * 128, col0 = by * 128;
  const __half* Ab = A;                        // W shared across images
  const __half* Bb = B + (size_t)((long long)img * bStride);

  // staging: 128 rows x 8 chunks per matrix = 1024 chunk-slots; 2 per thread each
  const __half* pA[2]; int dA[2];
  const __half* pB[2]; int dB[2];
#pragma unroll
  for (int it = 0; it < 2; ++it) {
    int e = it * 512 + tid, r = e >> 3, c = e & 7, sc = c ^ (r & 7);
    pA[it] = Ab + (size_t)(row0 + r) * K + sc * 8;
    pB[it] = Bb + (size_t)(col0 + r) * K + sc * 8;
    dA[it] = dB[it] = r * 64 + c * 8;
  }
  auto stage = [&](int buf, int kt) {
#pragma unroll
    for (int it = 0; it < 2; ++it)
      __builtin_amdgcn_global_load_lds(
          (const __attribute__((address_space(1))) unsigned int*)(pA[it] + kt),
          (__attribute__((address_space(3))) unsigned int*)(&smA[buf][dA[it]]),
          16, 0, 0);
#pragma unroll
    for (int it = 0; it < 2; ++it)
      __builtin_amdgcn_global_load_lds(
          (const __attribute__((address_space(1))) unsigned int*)(pB[it] + kt),
          (__attribute__((address_space(3))) unsigned int*)(&smB[buf][dB[it]]),
          16, 0, 0);
  };

  const int lr = lane & 15, kq = lane >> 4;
  f32x4 acc[4][2] = {};
  const int NT = K / 64;
  stage(0, 0);
  __syncthreads();
  int cur = 0;
  for (int t = 0; t < NT; ++t) {
    if (t + 1 < NT) stage(cur ^ 1, (t + 1) * 64);
#pragma unroll
    for (int kk = 0; kk < 2; ++kk) {
      const int ch = (kk * 4 + kq) ^ (lr & 7);
      f16x8 av[4], bv[2];
#pragma unroll
      for (int i = 0; i < 4; ++i)
        av[i] = *reinterpret_cast<const f16x8*>(&smA[cur][(wr * 64 + i * 16 + lr) * 64 + ch * 8]);
#pragma unroll
      for (int j = 0; j < 2; ++j)
        bv[j] = *reinterpret_cast<const f16x8*>(&smB[cur][(wc * 32 + j * 16 + lr) * 64 + ch * 8]);
      __builtin_amdgcn_s_setprio(1);
#pragma unroll
      for (int i = 0; i < 4; ++i)
#pragma unroll
        for (int j = 0; j < 2; ++j)
          acc[i][j] = __builtin_amdgcn_mfma_f32_16x16x32_f16(av[i], bv[j], acc[i][j], 0, 0, 0);
      __builtin_amdgcn_s_setprio(0);
    }
    __syncthreads();
    cur ^= 1;
  }
  epi.finalize(img, row0 + wr * 64, col0 + wc * 32, lane, acc);
}

extern "C" void kernel_launch(void* const* d_in, const int* in_sizes, int n_in,
                              void* d_out, int out_size, void* d_ws, size_t ws_size,
                              hipStream_t stream) {
  const float* x     = (const float*)d_in[0];
  const float* ln_g  = (const float*)d_in[1];
  const float* ln_b  = (const float*)d_in[2];
  const float* w_qkv = (const float*)d_in[3];
  const float* wc1   = (const float*)d_in[4];
  const float* wc2   = (const float*)d_in[5];
  const float* w1x1  = (const float*)d_in[6];
  const float* bn_g  = (const float*)d_in[7];
  const float* bn_b  = (const float*)d_in[8];
  const float* bn_m  = (const float*)d_in[9];
  const float* bn_v  = (const float*)d_in[10];
  const float* w_out = (const float*)d_in[11];
  const float* b_out = (const float*)d_in[12];
  float* out = (float*)d_out;

  const size_t MB = 1024 * 1024;
  char* ws = (char*)d_ws;
  __half* Pb = (__half*)ws;                   // region0 (64MB): P
  __half* ACb = (__half*)(ws + 64 * MB);      // region1 (64MB): AC (permuted channels)
  char* p = ws + 128 * MB;
  __half* XN    = (__half*)p; p += 2 * MB;            // 4096x256
  __half* WQKVT = (__half*)p; p += 1536 * 256 * 2;    // 1536x256
  __half* W1X1H = (__half*)p; p += 2 * MB;            // 1024x1024 (K permuted)
  __half* WOTT  = (__half*)p; p += 256 * 512 * 2;     // 256x512
  __half* Qb    = (__half*)p; p += 4 * MB;            // 32x1024x64 (scaled)
  __half* Kb    = (__half*)p; p += 4 * MB;            // 32x1024x64
  __half* Vtb   = (__half*)p; p += 4 * MB;            // 32x64x1024
  __half* Ob    = (__half*)p; p += 4 * MB;            // 4096x512

  prep_kernel<<<2048, 256, 0, stream>>>(w_qkv, w1x1, w_out, WQKVT, W1X1H, WOTT);
  ln_kernel<<<4096, 256, 0, stream>>>(x, ln_g, ln_b, XN);

  { EpiQKV e{Qb, Kb, Vtb};
    gemm_bt<128, 128, 64, 2, 4, 4, EpiQKV><<<dim3(32, 12, 1), 256, 0, stream>>>(
        XN, 0, WQKVT, 0, 256, e); }

  qkconv_kernel<<<dim3(8, 4, 32), 512, 0, stream>>>(Qb, Kb, wc1, wc2, ACb);

  { Epi1x1S e{Pb, bn_g, bn_b, bn_m, bn_v};
    gemm1x1<Epi1x1S><<<dim3(8, 8, 32), 512, 0, stream>>>(
        W1X1H, ACb, 1 << 20, 1024, e); }

  { EpiPV e{Ob};
    gemm_bt<64, 64, 64, 2, 2, 2, EpiPV><<<dim3(16, 1, 32), 256, 0, stream>>>(
        Pb, 1 << 20, Vtb, 65536, 1024, e); }

  { EpiOut e{out, b_out};
    gemm_bt<64, 64, 64, 2, 2, 2, EpiOut><<<dim3(64, 4, 1), 256, 0, stream>>>(
        Ob, 0, WOTT, 0, 512, e); }
}